// Round 2
// baseline (143.698 us; speedup 1.0000x reference)
//
#include <hip/hip_runtime.h>

// Fisher-Kolmogorov PDE: out = div(D * grad(u)) + rho * u * (1 - u)
// grad = central difference with replicate (edge) padding, applied twice.
// Shape: [B=4, C=1, D=192, H=192, W=192], float32.
// Vectorized: each thread computes a float4 along x (x0 = 4*tx).

#define NX 192

__global__ __launch_bounds__(192)
void fk_kernel(const float* __restrict__ u,
               const float* __restrict__ Dd,
               const float* __restrict__ rho,
               float* __restrict__ out)
{
    const int tx = threadIdx.x;              // 0..47 -> x0 = 4*tx
    const int ty = threadIdx.y;              // 0..3
    int bid = blockIdx.x;
    const int ytile = bid % 48;  bid /= 48;
    const int z = bid % NX;
    const int b = bid / NX;
    const int y = ytile * 4 + ty;
    const int x0 = tx * 4;

    const int rowb = ((b * NX + z) * NX + y) * NX;   // row base (x=0)
    const int base = rowb + x0;

    const float4 uc = *(const float4*)(u   + base);
    const float4 dc = *(const float4*)(Dd  + base);
    const float4 rc = *(const float4*)(rho + base);

    // ---------------- x axis ----------------
    float divx[4];
    if (tx > 0 && tx < 47) {
        // interior fast path: element e needs u[e-2..e+2], D[e-1],D[e+1]
        const float um2 = u[base - 2], um1 = u[base - 1];
        const float up1 = u[base + 4], up2 = u[base + 5];
        const float dm1 = Dd[base - 1], dp1 = Dd[base + 4];
        const float w[8] = {um2, um1, uc.x, uc.y, uc.z, uc.w, up1, up2};
        const float d6[6] = {dm1, dc.x, dc.y, dc.z, dc.w, dp1};
        #pragma unroll
        for (int i = 0; i < 4; ++i) {
            const float fp = d6[i + 2] * (w[i + 4] - w[i + 2]);
            const float fm = d6[i]     * (w[i + 2] - w[i]);
            divx[i] = (fp - fm) * 0.25f;
        }
    } else {
        // row-edge threads: full clamped semantics per element (cache-hot loads)
        #pragma unroll
        for (int i = 0; i < 4; ++i) {
            const int c   = x0 + i;
            const int jp  = (c + 1 < NX) ? (c + 1) : (NX - 1);
            const int jm  = (c - 1 > 0) ? (c - 1) : 0;
            const int jpp = (jp + 1 < NX) ? (jp + 1) : (NX - 1);
            const int jpm = jp - 1;
            const int jmp = jm + 1;
            const int jmm = (jm - 1 > 0) ? (jm - 1) : 0;
            const float fp = Dd[rowb + jp] * (u[rowb + jpp] - u[rowb + jpm]);
            const float fm = Dd[rowb + jm] * (u[rowb + jmp] - u[rowb + jmm]);
            divx[i] = (fp - fm) * 0.25f;
        }
    }

    // ---------------- y axis (stride NX) ----------------
    float4 divy4;
    {
        const int jp  = (y + 1 < NX) ? (y + 1) : (NX - 1);
        const int jm  = (y - 1 > 0) ? (y - 1) : 0;
        const int jpp = (jp + 1 < NX) ? (jp + 1) : (NX - 1);
        const int jpm = jp - 1;
        const int jmp = jm + 1;
        const int jmm = (jm - 1 > 0) ? (jm - 1) : 0;
        const float4 upp = *(const float4*)(u  + base + (jpp - y) * NX);
        const float4 upm = *(const float4*)(u  + base + (jpm - y) * NX);
        const float4 ump = *(const float4*)(u  + base + (jmp - y) * NX);
        const float4 umm = *(const float4*)(u  + base + (jmm - y) * NX);
        const float4 djp = *(const float4*)(Dd + base + (jp  - y) * NX);
        const float4 djm = *(const float4*)(Dd + base + (jm  - y) * NX);
        divy4.x = (djp.x * (upp.x - upm.x) - djm.x * (ump.x - umm.x)) * 0.25f;
        divy4.y = (djp.y * (upp.y - upm.y) - djm.y * (ump.y - umm.y)) * 0.25f;
        divy4.z = (djp.z * (upp.z - upm.z) - djm.z * (ump.z - umm.z)) * 0.25f;
        divy4.w = (djp.w * (upp.w - upm.w) - djm.w * (ump.w - umm.w)) * 0.25f;
    }

    // ---------------- z axis (stride NX*NX) ----------------
    float4 divz4;
    {
        const int S   = NX * NX;
        const int jp  = (z + 1 < NX) ? (z + 1) : (NX - 1);
        const int jm  = (z - 1 > 0) ? (z - 1) : 0;
        const int jpp = (jp + 1 < NX) ? (jp + 1) : (NX - 1);
        const int jpm = jp - 1;
        const int jmp = jm + 1;
        const int jmm = (jm - 1 > 0) ? (jm - 1) : 0;
        const float4 upp = *(const float4*)(u  + base + (jpp - z) * S);
        const float4 upm = *(const float4*)(u  + base + (jpm - z) * S);
        const float4 ump = *(const float4*)(u  + base + (jmp - z) * S);
        const float4 umm = *(const float4*)(u  + base + (jmm - z) * S);
        const float4 djp = *(const float4*)(Dd + base + (jp  - z) * S);
        const float4 djm = *(const float4*)(Dd + base + (jm  - z) * S);
        divz4.x = (djp.x * (upp.x - upm.x) - djm.x * (ump.x - umm.x)) * 0.25f;
        divz4.y = (djp.y * (upp.y - upm.y) - djm.y * (ump.y - umm.y)) * 0.25f;
        divz4.z = (djp.z * (upp.z - upm.z) - djm.z * (ump.z - umm.z)) * 0.25f;
        divz4.w = (djp.w * (upp.w - upm.w) - djm.w * (ump.w - umm.w)) * 0.25f;
    }

    // ---------------- reaction + store ----------------
    float4 o;
    o.x = divx[0] + divy4.x + divz4.x + rc.x * uc.x * (1.0f - uc.x);
    o.y = divx[1] + divy4.y + divz4.y + rc.y * uc.y * (1.0f - uc.y);
    o.z = divx[2] + divy4.z + divz4.z + rc.z * uc.z * (1.0f - uc.z);
    o.w = divx[3] + divy4.w + divz4.w + rc.w * uc.w * (1.0f - uc.w);
    *(float4*)(out + base) = o;
}

extern "C" void kernel_launch(void* const* d_in, const int* in_sizes, int n_in,
                              void* d_out, int out_size, void* d_ws, size_t ws_size,
                              hipStream_t stream) {
    const float* u   = (const float*)d_in[0];
    const float* Dd  = (const float*)d_in[1];
    const float* rho = (const float*)d_in[2];
    float* out = (float*)d_out;

    const int B = 4;
    dim3 block(48, 4, 1);                    // 192 threads, 4 rows of float4s
    const int grid = B * NX * (NX / 4);      // 36864 blocks
    fk_kernel<<<grid, block, 0, stream>>>(u, Dd, rho, out);
}

// Round 3
// 134.533 us; speedup vs baseline: 1.0681x; 1.0681x over previous
//
#include <hip/hip_runtime.h>

// Fisher-Kolmogorov PDE: out = div(D * grad(u)) + rho * u * (1 - u)
// grad = central difference with replicate padding, applied twice per axis.
// Shape: [B=4, C=1, D=192, H=192, W=192], float32.
//
// z-march kernel: each thread owns a float4 x-segment of one (x,y) column and
// marches ZCH z-planes with rolling register windows:
//   uz[0..4] = u[z-2..z+2] (own column), dz[0..2] = D[z-1..z+1].
// Per step: z-term entirely from registers; fresh loads = u[z+3], D[z+2],
// rho[z], 4 y-tap rows, 2 float2 + 2 scalar x-taps.

#define NX  192
#define SP  (NX * NX)
#define ZCH 16

__global__ __launch_bounds__(192, 4)
void fk_kernel(const float* __restrict__ u,
               const float* __restrict__ Dd,
               const float* __restrict__ rho,
               float* __restrict__ out)
{
    const int tx = threadIdx.x;              // 0..47 -> x0 = 4*tx
    const int ty = threadIdx.y;              // 0..3
    int bid = blockIdx.x;
    const int ytile = bid % (NX / 4);   bid /= (NX / 4);    // ytile fastest: plane sharing in L2
    const int zc    = bid % (NX / ZCH); bid /= (NX / ZCH);
    const int b     = bid;
    const int y  = ytile * 4 + ty;
    const int x0 = tx * 4;
    const int z0 = zc * ZCH;

    // y-axis clamped row indices (constant over the march)
    const int jpY  = (y + 1 < NX) ? y + 1 : NX - 1;
    const int jmY  = (y - 1 > 0) ? y - 1 : 0;
    const int jppY = (jpY + 1 < NX) ? jpY + 1 : NX - 1;
    const int jpmY = jpY - 1;
    const int jmpY = jmY + 1;
    const int jmmY = (jmY - 1 > 0) ? jmY - 1 : 0;
    const bool ld_jpm = (jpmY != y);         // true only at y == 191
    const bool ld_jmp = (jmpY != y);         // true only at y == 0
    const int o_jpp = (jppY - y) * NX;
    const int o_jmm = (jmmY - y) * NX;
    const int o_jpm = (jpmY - y) * NX;
    const int o_jmp = (jmpY - y) * NX;
    const int o_jp  = (jpY  - y) * NX;
    const int o_jm  = (jmY  - y) * NX;

    const int col0 = ((b * NX + z0) * NX + y) * NX + x0;
    const float* pu = u   + col0;
    const float* pd = Dd  + col0;
    const float* pr = rho + col0;
    float*       po = out + col0;

    // --- z-window init (clamped at domain start; z0 <= 176 so +1/+2 are safe) ---
    const int zm1 = (z0 - 1 > 0) ? z0 - 1 : 0;
    const int zm2 = (z0 - 2 > 0) ? z0 - 2 : 0;
    float4 uz0 = *(const float4*)(pu + (zm2 - z0) * SP);
    float4 uz1 = *(const float4*)(pu + (zm1 - z0) * SP);
    float4 uz2 = *(const float4*)(pu);
    float4 uz3 = *(const float4*)(pu + SP);
    float4 uz4 = *(const float4*)(pu + 2 * SP);
    float4 dz0 = *(const float4*)(pd + (zm1 - z0) * SP);
    float4 dz1 = *(const float4*)(pd);
    float4 dz2 = *(const float4*)(pd + SP);

    #pragma unroll 4
    for (int z = z0; z < z0 + ZCH; ++z) {
        // ---- issue this step's loads up front ----
        const int zp3 = (z + 3 < NX) ? z + 3 : NX - 1;   // next uz4
        const int zp2 = (z + 2 < NX) ? z + 2 : NX - 1;   // next dz2
        const float4 unx = *(const float4*)(pu + (zp3 - z) * SP);
        const float4 dnx = *(const float4*)(pd + (zp2 - z) * SP);
        const float4 rc  = *(const float4*)(pr);

        const float4 u_jpp = *(const float4*)(pu + o_jpp);
        const float4 u_jmm = *(const float4*)(pu + o_jmm);
        const float4 d_jp  = *(const float4*)(pd + o_jp);
        const float4 d_jm  = *(const float4*)(pd + o_jm);
        float4 u_jpm = uz2, u_jmp = uz2;                 // interior: row y itself
        if (ld_jpm) u_jpm = *(const float4*)(pu + o_jpm);
        if (ld_jmp) u_jmp = *(const float4*)(pu + o_jmp);

        float um2, um1, up1, up2, dm1, dp1;
        if (tx > 0) {
            const float2 t = *(const float2*)(pu - 2);
            um2 = t.x; um1 = t.y; dm1 = pd[-1];
        } else { um2 = uz2.x; um1 = uz2.x; dm1 = dz1.x; }
        if (tx < NX / 4 - 1) {
            const float2 t = *(const float2*)(pu + 4);
            up1 = t.x; up2 = t.y; dp1 = pd[4];
        } else { up1 = uz2.w; up2 = uz2.w; dp1 = dz1.w; }

        // ---- x term ----
        const float w[8]  = {um2, um1, uz2.x, uz2.y, uz2.z, uz2.w, up1, up2};
        const float d6[6] = {dm1, dz1.x, dz1.y, dz1.z, dz1.w, dp1};
        float divx[4];
        #pragma unroll
        for (int i = 0; i < 4; ++i) {
            const float fp = d6[i + 2] * (w[i + 4] - w[i + 2]);
            const float fm = d6[i]     * (w[i + 2] - w[i]);
            divx[i] = (fp - fm) * 0.25f;
        }
        // boundary fixups (replicate-pad semantics at x=0 and x=191)
        if (tx == 0)
            divx[0] = (d6[2] * (w[4] - w[2]) - dz1.x * (uz2.y - uz2.x)) * 0.25f;
        if (tx == NX / 4 - 1)
            divx[3] = (dz1.w * (uz2.w - uz2.z) - d6[3] * (w[5] - w[3])) * 0.25f;

        // ---- y term (full clamped-index semantics, no fixups needed) ----
        float4 divy;
        divy.x = (d_jp.x * (u_jpp.x - u_jpm.x) - d_jm.x * (u_jmp.x - u_jmm.x)) * 0.25f;
        divy.y = (d_jp.y * (u_jpp.y - u_jpm.y) - d_jm.y * (u_jmp.y - u_jmm.y)) * 0.25f;
        divy.z = (d_jp.z * (u_jpp.z - u_jpm.z) - d_jm.z * (u_jmp.z - u_jmm.z)) * 0.25f;
        divy.w = (d_jp.w * (u_jpp.w - u_jpm.w) - d_jm.w * (u_jmp.w - u_jmm.w)) * 0.25f;

        // ---- z term (registers; fixups only at z==0 / z==191) ----
        const bool zlo = (z == 0), zhi = (z == NX - 1);
        float4 divz;
        {
            const float apx = zhi ? uz2.x : uz4.x, bpx = zhi ? uz1.x : uz2.x;
            const float apy = zhi ? uz2.y : uz4.y, bpy = zhi ? uz1.y : uz2.y;
            const float apz = zhi ? uz2.z : uz4.z, bpz = zhi ? uz1.z : uz2.z;
            const float apw = zhi ? uz2.w : uz4.w, bpw = zhi ? uz1.w : uz2.w;
            const float amx = zlo ? uz3.x : uz2.x, bmx = zlo ? uz2.x : uz0.x;
            const float amy = zlo ? uz3.y : uz2.y, bmy = zlo ? uz2.y : uz0.y;
            const float amz = zlo ? uz3.z : uz2.z, bmz = zlo ? uz2.z : uz0.z;
            const float amw = zlo ? uz3.w : uz2.w, bmw = zlo ? uz2.w : uz0.w;
            divz.x = (dz2.x * (apx - bpx) - dz0.x * (amx - bmx)) * 0.25f;
            divz.y = (dz2.y * (apy - bpy) - dz0.y * (amy - bmy)) * 0.25f;
            divz.z = (dz2.z * (apz - bpz) - dz0.z * (amz - bmz)) * 0.25f;
            divz.w = (dz2.w * (apw - bpw) - dz0.w * (amw - bmw)) * 0.25f;
        }

        // ---- reaction + store ----
        float4 o;
        o.x = divx[0] + divy.x + divz.x + rc.x * uz2.x * (1.0f - uz2.x);
        o.y = divx[1] + divy.y + divz.y + rc.y * uz2.y * (1.0f - uz2.y);
        o.z = divx[2] + divy.z + divz.z + rc.z * uz2.z * (1.0f - uz2.z);
        o.w = divx[3] + divy.w + divz.w + rc.w * uz2.w * (1.0f - uz2.w);
        *(float4*)po = o;

        // ---- roll windows / advance pointers ----
        uz0 = uz1; uz1 = uz2; uz2 = uz3; uz3 = uz4; uz4 = unx;
        dz0 = dz1; dz1 = dz2; dz2 = dnx;
        pu += SP; pd += SP; pr += SP; po += SP;
    }
}

extern "C" void kernel_launch(void* const* d_in, const int* in_sizes, int n_in,
                              void* d_out, int out_size, void* d_ws, size_t ws_size,
                              hipStream_t stream) {
    const float* u   = (const float*)d_in[0];
    const float* Dd  = (const float*)d_in[1];
    const float* rho = (const float*)d_in[2];
    float* out = (float*)d_out;

    const int B = 4;
    dim3 block(NX / 4, 4, 1);                         // 192 threads
    const int grid = B * (NX / ZCH) * (NX / 4);       // 2304 blocks
    fk_kernel<<<grid, block, 0, stream>>>(u, Dd, rho, out);
}